// Round 1
// baseline (3012.168 us; speedup 1.0000x reference)
//
#include <hip/hip_runtime.h>
#include <hip/hip_bf16.h>
#include <cstdint>
#include <cstddef>

typedef __attribute__((ext_vector_type(8))) short short8;
typedef __attribute__((ext_vector_type(4))) float f32x4;
typedef unsigned short u16;

#define VOCAB 32000
#define EMB   512
#define HID   1024
#define GDIM  4096   // 4*HID
#define BATCH 16
#define SEQ   256
#define MTOT  4096   // BATCH*SEQ

static __device__ __forceinline__ u16 f2bf(float f) {
  unsigned u = __builtin_bit_cast(unsigned, f);
  u += 0x7fffu + ((u >> 16) & 1u);   // RNE
  return (u16)(u >> 16);
}

__global__ void cvt_bf16(const float* __restrict__ in, u16* __restrict__ out, long n) {
  long i = (long)blockIdx.x * blockDim.x + threadIdx.x;
  long stride = (long)gridDim.x * blockDim.x;
  for (; i < n; i += stride) out[i] = f2bf(in[i]);
}

__global__ void embed_gather(const int* __restrict__ x, const float* __restrict__ emb,
                             u16* __restrict__ A) {
  int m = blockIdx.x;                 // 0..4095  (m = b*SEQ + t)
  long base = (long)x[m] * EMB;
  for (int e = threadIdx.x; e < EMB; e += blockDim.x)
    A[(long)m * EMB + e] = f2bf(emb[base + e]);
}

// C[M][N] = A[M][K] * B[N][K]^T + bias[N], bf16 inputs, f32 out.
__global__ __launch_bounds__(256) void gemm_bt(
    const u16* __restrict__ A, const u16* __restrict__ B,
    const float* __restrict__ bias, float* __restrict__ C,
    int M, int N, int K)
{
  __shared__ u16 As[128 * 32];
  __shared__ u16 Bs[128 * 32];
  int tid  = threadIdx.x;
  int lane = tid & 63;
  int wid  = tid >> 6;
  int m0 = blockIdx.y * 128, n0 = blockIdx.x * 128;
  int wm = (wid >> 1) * 64, wn = (wid & 1) * 64;
  f32x4 acc[4][4] = {};

  int u0 = tid, u1 = tid + 256;              // staging slots in [0,512)
  int r0 = u0 >> 2, c0 = (u0 & 3) * 8;
  int r1 = u1 >> 2, c1 = (u1 & 3) * 8;

  int nk = K / 32;
  for (int kt = 0; kt < nk; ++kt) {
    int k = kt * 32;
    short8 va0 = *reinterpret_cast<const short8*>(A + (long)(m0 + r0) * K + k + c0);
    short8 va1 = *reinterpret_cast<const short8*>(A + (long)(m0 + r1) * K + k + c1);
    short8 vb0 = *reinterpret_cast<const short8*>(B + (long)(n0 + r0) * K + k + c0);
    short8 vb1 = *reinterpret_cast<const short8*>(B + (long)(n0 + r1) * K + k + c1);
    __syncthreads();                          // previous tile's LDS reads done
    reinterpret_cast<short8*>(As)[u0] = va0;
    reinterpret_cast<short8*>(As)[u1] = va1;
    reinterpret_cast<short8*>(Bs)[u0] = vb0;
    reinterpret_cast<short8*>(Bs)[u1] = vb1;
    __syncthreads();                          // writes visible
    short8 af[4], bf[4];
#pragma unroll
    for (int i = 0; i < 4; ++i) {
      af[i] = *reinterpret_cast<const short8*>(&As[(wm + i * 16 + (lane & 15)) * 32 + ((lane >> 4) << 3)]);
      bf[i] = *reinterpret_cast<const short8*>(&Bs[(wn + i * 16 + (lane & 15)) * 32 + ((lane >> 4) << 3)]);
    }
#pragma unroll
    for (int i = 0; i < 4; ++i)
#pragma unroll
      for (int j = 0; j < 4; ++j)
        acc[i][j] = __builtin_amdgcn_mfma_f32_16x16x32_bf16(af[i], bf[j], acc[i][j], 0, 0, 0);
  }

#pragma unroll
  for (int i = 0; i < 4; ++i) {
    int m = m0 + wm + i * 16 + ((lane >> 4) << 2);
#pragma unroll
    for (int j = 0; j < 4; ++j) {
      int n = n0 + wn + j * 16 + (lane & 15);
      float bv = bias[n];
#pragma unroll
      for (int jj = 0; jj < 4; ++jj)
        C[(long)(m + jj) * N + n] = acc[i][j][jj] + bv;
    }
  }
}

// One LSTM timestep. 64 blocks x 256 threads. Block owns h-cols [b16, b16+16);
// wave g computes gate-g preact tile [16 batch x 16 cols] via MFMA over K=1024.
__global__ __launch_bounds__(256) void lstm_step(
    const float* __restrict__ xg, const u16* __restrict__ Whh,
    const float* __restrict__ b_hh, const u16* __restrict__ h_in,
    u16* __restrict__ h_out, float* __restrict__ c,
    u16* __restrict__ h_all, int t)
{
  __shared__ float gates[4][16][16];
  int tid = threadIdx.x;
  int g = tid >> 6, lane = tid & 63;
  int col0 = blockIdx.x * 16;
  int gbase = g * HID + col0;          // gate-dim base for this wave
  int r  = lane & 15;                  // A row (batch) / B row (gate col)
  int ko = (lane >> 4) << 3;           // k offset within the 32-wide K step
  f32x4 acc = {0.f, 0.f, 0.f, 0.f};
  const short8* ap = reinterpret_cast<const short8*>(h_in + r * HID + ko);
  const short8* bp = reinterpret_cast<const short8*>(Whh + (long)(gbase + r) * HID + ko);
#pragma unroll
  for (int kk = 0; kk < HID / 32; ++kk) {
    short8 a = ap[kk * 4];
    short8 b = bp[kk * 4];
    acc = __builtin_amdgcn_mfma_f32_16x16x32_bf16(a, b, acc, 0, 0, 0);
  }
#pragma unroll
  for (int j = 0; j < 4; ++j) {
    int batch = ((lane >> 4) << 2) + j;
    int gd = gbase + (lane & 15);
    float pre = acc[j] + xg[((long)batch * SEQ + t) * GDIM + gd] + b_hh[gd];
    gates[g][batch][lane & 15] = pre;
  }
  __syncthreads();
  int b = tid >> 4, col = tid & 15;
  int hcol = col0 + col;
  float i_ = gates[0][b][col], f_ = gates[1][b][col];
  float g_ = gates[2][b][col], o_ = gates[3][b][col];
  i_ = 1.f / (1.f + __expf(-i_));
  f_ = 1.f / (1.f + __expf(-f_));
  g_ = tanhf(g_);
  o_ = 1.f / (1.f + __expf(-o_));
  int ci = b * HID + hcol;
  float cn = f_ * c[ci] + i_ * g_;
  c[ci] = cn;
  float h = o_ * tanhf(cn);
  u16 hb = f2bf(h);
  h_out[ci] = hb;
  h_all[((long)b * SEQ + t) * HID + hcol] = hb;
}

extern "C" void kernel_launch(void* const* d_in, const int* in_sizes, int n_in,
                              void* d_out, int out_size, void* d_ws, size_t ws_size,
                              hipStream_t stream) {
  const int*   x      = (const int*)d_in[0];
  const float* emb    = (const float*)d_in[1];
  const float* W_ih   = (const float*)d_in[2];
  const float* W_hh   = (const float*)d_in[3];
  const float* b_ih   = (const float*)d_in[4];
  const float* b_hh   = (const float*)d_in[5];
  const float* head_W = (const float*)d_in[6];
  const float* head_b = (const float*)d_in[7];
  float* out = (float*)d_out;

  char* ws = (char*)d_ws;
  size_t off = 0;
  auto alloc = [&](size_t bytes) -> void* {
    void* p = ws + off;
    off += (bytes + 255) & ~(size_t)255;
    return p;
  };
  u16*   Aemb   = (u16*)alloc((size_t)MTOT * EMB * 2);     //  4 MiB
  u16*   Wih_b  = (u16*)alloc((size_t)GDIM * EMB * 2);     //  4 MiB
  u16*   Whh_b  = (u16*)alloc((size_t)GDIM * HID * 2);     //  8 MiB
  u16*   HW_b   = (u16*)alloc((size_t)VOCAB * HID * 2);    // 62.5 MiB
  float* xg     = (float*)alloc((size_t)MTOT * GDIM * 4);  // 64 MiB
  u16*   h_all  = (u16*)alloc((size_t)MTOT * HID * 2);     //  8 MiB
  u16*   h_ping = (u16*)alloc((size_t)2 * BATCH * HID * 2);
  float* cst    = (float*)alloc((size_t)BATCH * HID * 4);

  hipMemsetAsync(h_ping, 0, (size_t)2 * BATCH * HID * 2, stream);
  hipMemsetAsync(cst, 0, (size_t)BATCH * HID * 4, stream);

  cvt_bf16<<<2048, 256, 0, stream>>>(W_ih, Wih_b, (long)GDIM * EMB);
  cvt_bf16<<<2048, 256, 0, stream>>>(W_hh, Whh_b, (long)GDIM * HID);
  cvt_bf16<<<4096, 256, 0, stream>>>(head_W, HW_b, (long)VOCAB * HID);
  embed_gather<<<MTOT, 256, 0, stream>>>(x, emb, Aemb);

  gemm_bt<<<dim3(GDIM / 128, MTOT / 128), 256, 0, stream>>>(
      Aemb, Wih_b, b_ih, xg, MTOT, GDIM, EMB);

  for (int t = 0; t < SEQ; ++t) {
    lstm_step<<<64, 256, 0, stream>>>(
        xg, Whh_b, b_hh,
        h_ping + (size_t)(t & 1) * BATCH * HID,
        h_ping + (size_t)((t + 1) & 1) * BATCH * HID,
        cst, h_all, t);
  }

  gemm_bt<<<dim3(VOCAB / 128, MTOT / 128), 256, 0, stream>>>(
      h_all, HW_b, head_b, out, MTOT, VOCAB, HID);
}